// Round 8
// baseline (178.548 us; speedup 1.0000x reference)
//
#include <hip/hip_runtime.h>
#include <stdint.h>

#define WW 48
#define NQ 2304             // 48*48
#define NCH 8               // key chunks (6 columns each)
#define NWT 144             // wave-tiles of 256 queries (16 bh * 9 qt)
#define SCL 0.51011868f     // 8^-0.5 * log2(e)  (folded so softmax = exp2)
#define SHIFT 17.312340491f // 12 * log2(e)      (fixed-shift softmax)

__device__ __forceinline__ float rdl(float v, int l) {
    return __int_as_float(__builtin_amdgcn_readlane(__float_as_int(v), l));
}
__device__ __forceinline__ float dot8(float4 a, float4 b, float4 c, float4 d) {
    return a.x*b.x + a.y*b.y + a.z*b.z + a.w*b.w
         + c.x*d.x + c.y*d.y + c.z*d.z + c.w*d.w;
}

// ---------------------------------------------------------------------------
// attn: 4 queries/lane, 256 q/wave, 1-wave blocks (__launch_bounds__(64,1)
// stops the R7 spill: compiler targeted 8 waves/SIMD -> 48 VGPRs -> scratch).
// Keys delivered via v_readlane broadcast: lanes 0..47 stage 48 keys' KV in
// VGPRs (double-buffered across rounds); each K/V element is extracted to an
// SGPR with readlane and consumed as the one-SGPR operand of each fma.
// No per-lane KV bytes (R3/R5 wall), no SMEM drain (R6 wall).
// dt = two parallel 4-fma trees (short critical path); 36 live chains/key.
// logit = q.k + q.rel_w[x2-x+47] + q.rel_h[y2-y+47]; p = exp2(logit'-SHIFT)
// grid 1152 = 16 bh * 9 qt * 8 kc, 64 thr. P slab [9][256] per (kc,wavetile).
// ---------------------------------------------------------------------------
__global__ __launch_bounds__(64, 1) void attn_kernel(const float* __restrict__ in,
                                                     const float* __restrict__ relw,
                                                     const float* __restrict__ relh,
                                                     float* __restrict__ P) {
    const int bx = blockIdx.x;
    const int bh = bx / 72;
    const int rem = bx - bh * 72;
    const int qt = rem >> 3;           // 0..8
    const int kc = rem & 7;            // 0..7
    const int lane = threadIdx.x;
    const int b = bh >> 3, h = bh & 7;

    // ---- this lane's four queries ----
    float4 qa[4], qb[4];
    int xq[4], yq[4];
#pragma unroll
    for (int j = 0; j < 4; ++j) {
        const int n = qt * 256 + j * 64 + lane;
        const int y = n / WW;
        yq[j] = y; xq[j] = n - y * WW;
        const float* qp = in + ((size_t)(b * NQ + n) * 192 + h * 8);
        float4 a = *(const float4*)qp, bb = *(const float4*)(qp + 4);
        a.x *= SCL; a.y *= SCL; a.z *= SCL; a.w *= SCL;
        bb.x *= SCL; bb.y *= SCL; bb.z *= SCL; bb.w *= SCL;
        qa[j] = a; qb[j] = bb;
    }

    // ---- qw per (query, chunk column) ----
    float qw[4][6];
#pragma unroll
    for (int j = 0; j < 4; ++j)
#pragma unroll
        for (int c = 0; c < 6; ++c) {
            const float* rw = relw + (kc * 6 + c - xq[j] + 47) * 8;
            qw[j][c] = dot8(qa[j], *(const float4*)rw,
                            qb[j], *(const float4*)(rw + 4));
        }

    float l[4] = {0, 0, 0, 0};
    float A[4][8] = {{0}};

    // ---- lane -> staged key within a round (8 rows x 6 cols = 48 keys) ----
    int lr = lane / 6, lc = lane - lr * 6;
    if (lane >= 48) { lr = 7; lc = 5; }          // clamp (unused by readlane)
    const float* kvbase = in + ((size_t)(b * NQ + lr * 48 + kc * 6 + lc) * 192
                                + 64 + h * 8);
    const size_t RSTRIDE = (size_t)8 * 48 * 192;  // 8 key-rows per round

    // double-buffered KV staging
    float4 ck0 = *(const float4*)kvbase;
    float4 ck1 = *(const float4*)(kvbase + 4);
    float4 cv0 = *(const float4*)(kvbase + 64);
    float4 cv1 = *(const float4*)(kvbase + 68);

#pragma unroll 1
    for (int R = 0; R < 6; ++R) {
        const float* np = kvbase + (size_t)(R < 5 ? R + 1 : 5) * RSTRIDE;
        float4 nk0 = *(const float4*)np;
        float4 nk1 = *(const float4*)(np + 4);
        float4 nv0 = *(const float4*)(np + 64);
        float4 nv1 = *(const float4*)(np + 68);

#pragma unroll 2
        for (int row = 0; row < 8; ++row) {
            const int y2 = R * 8 + row;
            float qh[4];
#pragma unroll
            for (int j = 0; j < 4; ++j) {
                const float* rh = relh + (y2 - yq[j] + 47) * 8;
                qh[j] = dot8(qa[j], *(const float4*)rh,
                             qb[j], *(const float4*)(rh + 4)) - SHIFT;
            }
#pragma unroll
            for (int c = 0; c < 6; ++c) {
                const int idx = row * 6 + c;     // wave-uniform
                const float k0 = rdl(ck0.x, idx), k1 = rdl(ck0.y, idx);
                const float k2 = rdl(ck0.z, idx), k3 = rdl(ck0.w, idx);
                const float k4 = rdl(ck1.x, idx), k5 = rdl(ck1.y, idx);
                const float k6 = rdl(ck1.z, idx), k7 = rdl(ck1.w, idx);
                const float v0 = rdl(cv0.x, idx), v1 = rdl(cv0.y, idx);
                const float v2 = rdl(cv0.z, idx), v3 = rdl(cv0.w, idx);
                const float v4 = rdl(cv1.x, idx), v5 = rdl(cv1.y, idx);
                const float v6 = rdl(cv1.z, idx), v7 = rdl(cv1.w, idx);
#pragma unroll
                for (int j = 0; j < 4; ++j) {
                    // two parallel 4-deep fma trees -> short critical path
                    float dA = fmaf(qa[j].x, k0, fmaf(qa[j].y, k1,
                               fmaf(qa[j].z, k2, qa[j].w * k3)));
                    float dB = fmaf(qb[j].x, k4, fmaf(qb[j].y, k5,
                               fmaf(qb[j].z, k6, qb[j].w * k7)));
                    const float p = __builtin_amdgcn_exp2f(
                        (qh[j] + qw[j][c]) + (dA + dB));
                    l[j] += p;
                    A[j][0] = fmaf(p, v0, A[j][0]); A[j][1] = fmaf(p, v1, A[j][1]);
                    A[j][2] = fmaf(p, v2, A[j][2]); A[j][3] = fmaf(p, v3, A[j][3]);
                    A[j][4] = fmaf(p, v4, A[j][4]); A[j][5] = fmaf(p, v5, A[j][5]);
                    A[j][6] = fmaf(p, v6, A[j][6]); A[j][7] = fmaf(p, v7, A[j][7]);
                }
            }
        }
        ck0 = nk0; ck1 = nk1; cv0 = nv0; cv1 = nv1;
    }

    // ---- store partials: slab per (kc, wave-tile), layout [9][256] ----
    const int wt = bh * 9 + qt;
    float* pb = P + (size_t)(kc * NWT + wt) * 2304;
#pragma unroll
    for (int j = 0; j < 4; ++j) {
        pb[j * 64 + lane] = l[j];
#pragma unroll
        for (int e = 0; e < 8; ++e)
            pb[(1 + e) * 256 + j * 64 + lane] = A[j][e];
    }
}

// ---------------------------------------------------------------------------
// merge: sum 8 chunk-partials per query, normalize, write out[b][n][h*8+j]
// ---------------------------------------------------------------------------
__global__ __launch_bounds__(256) void merge_kernel(const float* __restrict__ P,
                                                    float* __restrict__ out) {
    const int t = blockIdx.x * 256 + threadIdx.x;   // [0, 36864)
    const int wt = t >> 8, q = t & 255;
    float s[9];
#pragma unroll
    for (int j = 0; j < 9; ++j) s[j] = 0.0f;
#pragma unroll
    for (int kcc = 0; kcc < NCH; ++kcc) {
        const float* pb = P + (size_t)(kcc * NWT + wt) * 2304;
#pragma unroll
        for (int j = 0; j < 9; ++j) s[j] += pb[j * 256 + q];
    }
    const float inv = 1.0f / s[0];
    const int bh = wt / 9;
    const int qtl = wt - bh * 9;
    const int n = qtl * 256 + q;
    const int b = bh >> 3, h = bh & 7;
    float* op = out + ((size_t)(b * NQ + n) * 64 + h * 8);
    ((float4*)op)[0] = make_float4(s[1] * inv, s[2] * inv, s[3] * inv, s[4] * inv);
    ((float4*)op)[1] = make_float4(s[5] * inv, s[6] * inv, s[7] * inv, s[8] * inv);
}

extern "C" void kernel_launch(void* const* d_in, const int* in_sizes, int n_in,
                              void* d_out, int out_size, void* d_ws, size_t ws_size,
                              hipStream_t stream) {
    const float* in   = (const float*)d_in[0];
    const float* relw = (const float*)d_in[1];
    const float* relh = (const float*)d_in[2];
    float* P   = (float*)d_ws;    // 8 * 144 * 2304 * 4 B = 10.6 MB (proven fit)
    float* out = (float*)d_out;

    attn_kernel<<<16 * 9 * 8, 64, 0, stream>>>(in, relw, relh, P);
    merge_kernel<<<144, 256, 0, stream>>>(P, out);
}